// Round 1
// baseline (1168.150 us; speedup 1.0000x reference)
//
#include <hip/hip_runtime.h>

// dijetReinforceLayer: out[n,o,s] = b[o] + sum_c ( W[o,c,0]*x[n,c,2s]
//                                               + W[o,c,1]*x[n,c,2s+1]
//                                               + W[o,c,2]*d[n,c,s] )
// N=131072, ND=32, NPAIR=6, KS=3.
//
// Strategy: memory-bound (384 MiB traffic vs 4.8 GFLOP). One thread per
// (n, s): din (96 floats) lives in VGPRs, W accesses are wave-uniform ->
// SGPR scalar loads (constant cache), zero LDS. Lane order (s fastest)
// makes the 32 upfront loads cover a contiguous 16 KB region per wave.

#define ND 32
#define NPAIR 6

__global__ __launch_bounds__(256, 4) void dijet_kernel(
    const float* __restrict__ x,   // [N, 32, 12]
    const float* __restrict__ d,   // [N, 32, 6]
    const float* __restrict__ W,   // [32, 32, 3]
    const float* __restrict__ b,   // [32]
    float* __restrict__ out,       // [N, 32, 6]
    int total)                     // N * 6
{
    int t = blockIdx.x * blockDim.x + threadIdx.x;
    if (t >= total) return;
    int n = t / 6;
    int s = t - n * 6;

    const float* xp = x + (size_t)n * (ND * 2 * NPAIR) + 2 * s;  // x[n, 0, 2s]
    const float* dp = d + (size_t)n * (ND * NPAIR) + s;          // d[n, 0, s]

    // Load this (n,s)'s din into registers: x even/odd pair + d, per channel.
    float xe[ND], xo[ND], dd[ND];
#pragma unroll
    for (int c = 0; c < ND; ++c) {
        float2 p = *reinterpret_cast<const float2*>(xp + c * (2 * NPAIR));
        xe[c] = p.x;
        xo[c] = p.y;
        dd[c] = dp[c * NPAIR];
    }

    float* op = out + (size_t)n * (ND * NPAIR) + s;  // out[n, 0, s]

    // o-loop: W row is wave-uniform -> scalar loads. 3 independent FMA
    // chains per o hide the 4-cycle dependent-FMA latency.
#pragma unroll 2
    for (int o = 0; o < ND; ++o) {
        const float* w = W + o * (ND * 3);
        float a0 = 0.f, a1 = 0.f, a2 = 0.f;
#pragma unroll
        for (int c = 0; c < ND; ++c) {
            a0 = fmaf(w[c * 3 + 0], xe[c], a0);
            a1 = fmaf(w[c * 3 + 1], xo[c], a1);
            a2 = fmaf(w[c * 3 + 2], dd[c], a2);
        }
        op[o * NPAIR] = a0 + a1 + a2 + b[o];
    }
}

extern "C" void kernel_launch(void* const* d_in, const int* in_sizes, int n_in,
                              void* d_out, int out_size, void* d_ws, size_t ws_size,
                              hipStream_t stream) {
    const float* x = (const float*)d_in[0];
    const float* d = (const float*)d_in[1];
    const float* W = (const float*)d_in[2];
    const float* b = (const float*)d_in[3];
    float* out = (float*)d_out;

    int N = in_sizes[0] / (ND * 2 * NPAIR);
    int total = N * NPAIR;

    dim3 block(256);
    dim3 grid((total + block.x - 1) / block.x);
    dijet_kernel<<<grid, block, 0, stream>>>(x, d, W, b, out, total);
}

// Round 2
// 470.761 us; speedup vs baseline: 2.4814x; 2.4814x over previous
//
#include <hip/hip_runtime.h>

// dijetReinforceLayer: out[n,o,s] = b[o] + sum_c ( W[o,c,0]*x[n,c,2s]
//                                               + W[o,c,1]*x[n,c,2s+1]
//                                               + W[o,c,2]*d[n,c,s] )
// N=131072, ND=32, NPAIR=6, KS=3.
//
// R1 design notes:
//  - R0 failed because the compiler rematerialized the 96 din values
//    (VGPR_Count=64, FETCH 2.27 GB vs 0.3 GB ideal). Fix: hold 96
//    ACCUMULATORS in registers (cannot be rematerialized) and stream din:
//    per c, load {x_even, x_odd, d} once, do 96 FMAs. W/b accesses are
//    wave-uniform (loop counters only) -> s_load from scalar cache.
//  - Stores: 192-thread block owns exactly 32 samples; outputs staged in
//    padded LDS (stride 200 floats -> <=3-way write conflicts), then
//    written as fully-coalesced float4 streams (guaranteed full-line HBM
//    writes regardless of L2 eviction timing).

#define ND 32
#define NPAIR 6
#define SPB 32               // samples per block
#define BT 192               // block threads = SPB * NPAIR
#define OSTRIDE 200          // LDS floats per sample (192 + 8 pad)

__global__ __launch_bounds__(BT, 3) void dijet_kernel(
    const float* __restrict__ x,   // [N, 32, 12]
    const float* __restrict__ d,   // [N, 32, 6]
    const float* __restrict__ W,   // [32, 32, 3]
    const float* __restrict__ b,   // [32]
    float* __restrict__ out,       // [N, 32, 6]
    int N)
{
    __shared__ float obuf[SPB * OSTRIDE];   // 25.6 KB

    const int t  = threadIdx.x;
    const int nl = t / NPAIR;               // local sample 0..31
    const int s  = t - nl * NPAIR;          // slot 0..5
    const int n  = blockIdx.x * SPB + nl;

    // 96 accumulators: acc{0,1,2}[o]. These are live across the whole
    // c-loop and cannot be rematerialized -> din is loaded exactly once.
    float acc0[ND], acc1[ND], acc2[ND];
#pragma unroll
    for (int o = 0; o < ND; ++o) { acc0[o] = 0.f; acc1[o] = 0.f; acc2[o] = 0.f; }

    if (n < N) {
        const float* xp = x + (size_t)n * (ND * 2 * NPAIR) + 2 * s; // x[n,0,2s]
        const float* dp = d + (size_t)n * (ND * NPAIR) + s;         // d[n,0,s]

        // Stream over input channels; 3 loads then 96 FMAs per c.
        // unroll 8 keeps the body ~8 KB (I$-resident) with ample load batching.
#pragma unroll 8
        for (int c = 0; c < ND; ++c) {
            float2 p = *reinterpret_cast<const float2*>(xp + c * (2 * NPAIR));
            float dv = dp[c * NPAIR];
            const float* wc = W + c * 3;    // W[0, c, 0]; o-stride = 96 floats
#pragma unroll
            for (int o = 0; o < ND; ++o) {
                acc0[o] = fmaf(wc[o * (ND * 3) + 0], p.x, acc0[o]);
                acc1[o] = fmaf(wc[o * (ND * 3) + 1], p.y, acc1[o]);
                acc2[o] = fmaf(wc[o * (ND * 3) + 2], dv, acc2[o]);
            }
        }

        // Epilogue into LDS at [nl][o*6 + s] (padded sample stride).
        float* ob = obuf + nl * OSTRIDE + s;
#pragma unroll
        for (int o = 0; o < ND; ++o)
            ob[o * NPAIR] = acc0[o] + acc1[o] + acc2[o] + b[o];
    }

    __syncthreads();

    // Coalesced writeback: 32 samples * 192 floats = 1536 float4 per block.
    // Thread t writes float4 indices {t + k*192}: each wave's instruction
    // covers 1 KB contiguous global memory.
    const int base = blockIdx.x * SPB;
#pragma unroll
    for (int k = 0; k < 8; ++k) {
        int f4 = t + k * BT;                 // 0..1535
        int F  = f4 * 4;                     // flat float index in block tile
        int ns = F / 192;                    // sample within block
        int wi = F - ns * 192;               // float offset within sample
        int gn = base + ns;
        if (gn < N) {
            float4 v = *reinterpret_cast<const float4*>(&obuf[ns * OSTRIDE + wi]);
            *reinterpret_cast<float4*>(out + (size_t)gn * (ND * NPAIR) + wi) = v;
        }
    }
}

extern "C" void kernel_launch(void* const* d_in, const int* in_sizes, int n_in,
                              void* d_out, int out_size, void* d_ws, size_t ws_size,
                              hipStream_t stream) {
    const float* x = (const float*)d_in[0];
    const float* d = (const float*)d_in[1];
    const float* W = (const float*)d_in[2];
    const float* b = (const float*)d_in[3];
    float* out = (float*)d_out;

    int N = in_sizes[0] / (ND * 2 * NPAIR);
    int blocks = (N + SPB - 1) / SPB;

    dijet_kernel<<<blocks, BT, 0, stream>>>(x, d, W, b, out, N);
}

// Round 3
// 393.409 us; speedup vs baseline: 2.9693x; 1.1966x over previous
//
#include <hip/hip_runtime.h>

// dijetReinforceLayer via MFMA.
// out[n,o,s] = b[o] + sum_{c,j} W[o,c,j] * din[n,c,s,j],
//   din[...,0..1] = x[n,c,2s..2s+1], din[...,2] = d[n,c,s].
// GEMM view: out[o, col] = sum_k A[o,k] B[k,col], col=(n,s), K=96.
// K reorder: k = 2c+j for j in {0,1} (x part, pairs contiguous), k = 64+c for j=2 (d part).
//
// R2 post-mortem: scalar-FMA path is issue-bound (2.42e9 FMA = 31 us floor,
// 51% VALUBusy at 228 us). MFMA collapses compute to ~5 us -> memory-bound.
// Fragment mappings per verified m89/m91/m97 chain (16x16x32_bf16):
//   A[m=lane&15][k=(lane>>4)*8+j], B[k=(lane>>4)*8+j][n=lane&15],
//   C/D: col=lane&15, row=(lane>>4)*4+reg.

#define ND 32
#define NPAIR 6
#define SPB 32                  // samples per block
#define BT 192                  // 3 waves
#define COLS (SPB * NPAIR)      // 192
#define KSTR 104                // bf16 row stride (96 + 8 pad)
#define OSTR 200                // obuf dword stride per sample (192 + 8 pad)

typedef __attribute__((ext_vector_type(8))) short bf16x8;
typedef __attribute__((ext_vector_type(4))) float f32x4;

// pack two fp32 -> two bf16 (truncate): low16 = bf16(lo), high16 = bf16(hi)
__device__ __forceinline__ unsigned pack2(float lo, float hi) {
    return __builtin_amdgcn_perm(__float_as_uint(hi), __float_as_uint(lo), 0x07060302u);
}
__device__ __forceinline__ unsigned short bf16t(float v) {
    return (unsigned short)(__float_as_uint(v) >> 16);
}

__global__ __launch_bounds__(BT) void dijet_mfma(
    const float* __restrict__ x,    // [N, 32, 12]
    const float* __restrict__ d,    // [N, 32, 6]
    const float* __restrict__ W,    // [32, 32, 3]
    const float* __restrict__ bias, // [32]
    float* __restrict__ out,        // [N, 32, 6]
    int N)
{
    // B: COLS*KSTR bf16 = 39936 B ; A: 32*KSTR bf16 = 6656 B. obuf (25600 B)
    // reuses the B region after a sync. Total 46592 B -> 3 blocks/CU.
    __shared__ __align__(16) unsigned char smem[COLS * KSTR * 2 + ND * KSTR * 2];
    unsigned short* Bb = (unsigned short*)smem;                    // [col][k]
    unsigned short* Ab = (unsigned short*)(smem + COLS * KSTR * 2);// [o][k]
    float* obuf = (float*)smem;                                    // [ls][OSTR]

    const int t  = threadIdx.x;
    const int n0 = blockIdx.x * SPB;
    const bool full = (n0 + SPB <= N);

    // ---- stage x: 32*384 floats, 16 float4/thread, fully coalesced ----
    const float* xb = x + (size_t)n0 * (ND * 2 * NPAIR);
#pragma unroll
    for (int i = 0; i < 16; ++i) {
        int fl = 4 * (t + i * BT);       // float offset in block chunk
        int ls = fl / 384;               // local sample (float4 never crosses)
        int r  = fl % 384;
        int c  = r / 12;
        int e  = r % 12;                 // 0,4,8
        float4 v;
        if (full || n0 + ls < N) v = *(const float4*)(xb + fl);
        else v = make_float4(0.f, 0.f, 0.f, 0.f);
        int col0 = ls * NPAIR + (e >> 1);
        *(unsigned*)&Bb[col0 * KSTR + 2 * c]       = pack2(v.x, v.y);
        *(unsigned*)&Bb[(col0 + 1) * KSTR + 2 * c] = pack2(v.z, v.w);
    }

    // ---- stage d: 32*192 floats, 8 float4/thread, per-element scatter ----
    const float* db = d + (size_t)n0 * (ND * NPAIR);
#pragma unroll
    for (int i = 0; i < 8; ++i) {
        int fl = 4 * (t + i * BT);
        float4 v;
        if (full) v = *(const float4*)(db + fl);
        else {
            float tmp[4];
#pragma unroll
            for (int m = 0; m < 4; ++m) {
                int f = fl + m;
                tmp[m] = (n0 + f / 192 < N) ? db[f] : 0.f;
            }
            v = make_float4(tmp[0], tmp[1], tmp[2], tmp[3]);
        }
        float vv[4] = {v.x, v.y, v.z, v.w};
#pragma unroll
        for (int m = 0; m < 4; ++m) {
            int f  = fl + m;
            int ls = f / 192;
            int r  = f % 192;
            int c  = r / 6;
            int s  = r % 6;
            Bb[(ls * NPAIR + s) * KSTR + 64 + c] = bf16t(vv[m]);
        }
    }

    // ---- stage W -> A (reordered k), 16 elements/thread ----
#pragma unroll
    for (int i = 0; i < 16; ++i) {
        int idx = t + i * BT;            // [0, 3072)
        int o = idx / 96;
        int r = idx % 96;
        int c = r / 3;
        int j = r % 3;
        int k = (j == 2) ? (64 + c) : (2 * c + j);
        Ab[o * KSTR + k] = bf16t(W[idx]);
    }

    __syncthreads();

    // ---- MFMA: wave w owns col-tiles 4w..4w+3 (16 cols each), both o-tiles ----
    const int w     = t >> 6;
    const int l     = t & 63;
    const int row16 = l & 15;
    const int quad  = l >> 4;
    const int ct0   = w * 4;

    // A fragments: [o-tile][k-step]
    bf16x8 Af[2][3];
#pragma unroll
    for (int ot = 0; ot < 2; ++ot) {
        const unsigned short* ap = Ab + (ot * 16 + row16) * KSTR + quad * 8;
#pragma unroll
        for (int ks = 0; ks < 3; ++ks)
            Af[ot][ks] = *(const bf16x8*)(ap + ks * 32);
    }

    // accumulators init with bias: reg r of (ct, ot) holds o = ot*16 + quad*4 + r
    float4 bv0 = *(const float4*)(bias + quad * 4);
    float4 bv1 = *(const float4*)(bias + 16 + quad * 4);
    f32x4 acc[4][2];
#pragma unroll
    for (int ct = 0; ct < 4; ++ct) {
        acc[ct][0] = (f32x4){bv0.x, bv0.y, bv0.z, bv0.w};
        acc[ct][1] = (f32x4){bv1.x, bv1.y, bv1.z, bv1.w};
    }

#pragma unroll
    for (int ct = 0; ct < 4; ++ct) {
        int col = (ct0 + ct) * 16 + row16;
        const unsigned short* bp = Bb + col * KSTR + quad * 8;
        bf16x8 B0 = *(const bf16x8*)(bp);
        bf16x8 B1 = *(const bf16x8*)(bp + 32);
        bf16x8 B2 = *(const bf16x8*)(bp + 64);
        acc[ct][0] = __builtin_amdgcn_mfma_f32_16x16x32_bf16(Af[0][0], B0, acc[ct][0], 0, 0, 0);
        acc[ct][0] = __builtin_amdgcn_mfma_f32_16x16x32_bf16(Af[0][1], B1, acc[ct][0], 0, 0, 0);
        acc[ct][0] = __builtin_amdgcn_mfma_f32_16x16x32_bf16(Af[0][2], B2, acc[ct][0], 0, 0, 0);
        acc[ct][1] = __builtin_amdgcn_mfma_f32_16x16x32_bf16(Af[1][0], B0, acc[ct][1], 0, 0, 0);
        acc[ct][1] = __builtin_amdgcn_mfma_f32_16x16x32_bf16(Af[1][1], B1, acc[ct][1], 0, 0, 0);
        acc[ct][1] = __builtin_amdgcn_mfma_f32_16x16x32_bf16(Af[1][2], B2, acc[ct][1], 0, 0, 0);
    }

    __syncthreads();   // all B reads done; safe to overwrite with obuf

    // ---- epilogue: C/D -> padded LDS out-layout ----
#pragma unroll
    for (int ct = 0; ct < 4; ++ct) {
        int col = (ct0 + ct) * 16 + row16;
        int ls  = col / 6;
        int s   = col % 6;
        float* ob = obuf + ls * OSTR + s;
#pragma unroll
        for (int ot = 0; ot < 2; ++ot) {
            int o0 = ot * 16 + quad * 4;
            ob[(o0 + 0) * NPAIR] = acc[ct][ot].x;
            ob[(o0 + 1) * NPAIR] = acc[ct][ot].y;
            ob[(o0 + 2) * NPAIR] = acc[ct][ot].z;
            ob[(o0 + 3) * NPAIR] = acc[ct][ot].w;
        }
    }

    __syncthreads();

    // ---- coalesced float4 writeback (proven in R2: exact-ideal WRITE_SIZE) ----
    float* og = out + (size_t)n0 * (ND * NPAIR);
#pragma unroll
    for (int k = 0; k < 8; ++k) {
        int F  = 4 * (t + k * BT);       // [0, 6144)
        int ns = F / 192;
        int wi = F % 192;
        if (full || n0 + ns < N) {
            float4 v = *(const float4*)(obuf + ns * OSTR + wi);
            *(float4*)(og + ns * 192 + wi) = v;
        }
    }
}

extern "C" void kernel_launch(void* const* d_in, const int* in_sizes, int n_in,
                              void* d_out, int out_size, void* d_ws, size_t ws_size,
                              hipStream_t stream) {
    const float* x = (const float*)d_in[0];
    const float* d = (const float*)d_in[1];
    const float* W = (const float*)d_in[2];
    const float* b = (const float*)d_in[3];
    float* out = (float*)d_out;

    int N = in_sizes[0] / (ND * 2 * NPAIR);
    int blocks = (N + SPB - 1) / SPB;

    dijet_mfma<<<blocks, BT, 0, stream>>>(x, d, W, b, out, N);
}